// Round 1
// baseline (105.030 us; speedup 1.0000x reference)
//
#include <hip/hip_runtime.h>

// Pixel shuffle (depth-to-space), r=2:
//   out[b, x, y, c] = in[b, x>>1, y>>1, ((y&1)*2 + (x&1))*16 + c]
// Input  [16, 256, 256, 64] f32, Output [16, 512, 512, 16] f32.
// Pure permutation; each 16-float input chunk -> contiguous 16-float output
// chunk. Thread = one output float4 (grid-stride): writes perfectly
// coalesced, reads in 64B-contiguous segments.

__global__ __launch_bounds__(256) void Conv2DSubPixel_44032004718623_kernel(
    const float4* __restrict__ in, float4* __restrict__ out, int n4) {
    int stride = gridDim.x * blockDim.x;
    for (int o4 = blockIdx.x * blockDim.x + threadIdx.x; o4 < n4; o4 += stride) {
        int c4 = o4 & 3;        // which float4 within the 16-float chunk
        int t  = o4 >> 2;       // (b, x, y)
        int y  = t & 511;
        int t2 = t >> 9;
        int x  = t2 & 511;
        int b  = t2 >> 9;
        int h = x >> 1, i = x & 1;
        int w = y >> 1, j = y & 1;
        // input float4 index: pixel*(64/4) + (2j+i)*4 + c4
        int pix  = ((b << 8 | h) << 8) | w;
        int iidx = (pix << 4) + (((j << 1) | i) << 2) + c4;
        out[o4] = in[iidx];
    }
}

extern "C" void kernel_launch(void* const* d_in, const int* in_sizes, int n_in,
                              void* d_out, int out_size, void* d_ws, size_t ws_size,
                              hipStream_t stream) {
    const float4* in = (const float4*)d_in[0];
    float4* out = (float4*)d_out;
    int n4 = out_size / 4;  // 16,777,216 float4s
    dim3 block(256);
    dim3 grid(2048);        // 8 blocks/CU, grid-stride covers the rest
    hipLaunchKernelGGL(Conv2DSubPixel_44032004718623_kernel, grid, block, 0,
                       stream, in, out, n4);
}

// Round 2
// 94.488 us; speedup vs baseline: 1.1116x; 1.1116x over previous
//
#include <hip/hip_runtime.h>

// Pixel shuffle (depth-to-space), r=2:
//   out[b, x, y, c] = in[b, x>>1, y>>1, ((y&1)*2 + (x&1))*16 + c]
// Input  [16, 256, 256, 64] f32, Output [16, 512, 512, 16] f32.
//
// INPUT-indexed mapping (one thread per input float4):
//   reads:  64 consecutive float4/wave = 1 KB fully coalesced
//   writes: input sub-chunk (i,j) of pixel (h,w) -> out row 2h+i, col 2w+j;
//           the (j=0, j=1) pair forms 8 consecutive float4s starting at an
//           index divisible by 8 -> 128 B line-aligned full-line segments.
// Both directions move only complete cache lines; no cross-wave line sharing.
// Nontemporal: strictly streaming data (each byte touched exactly once).

typedef float f4 __attribute__((ext_vector_type(4)));

__global__ __launch_bounds__(256) void Conv2DSubPixel_44032004718623_kernel(
    const f4* __restrict__ in, f4* __restrict__ out, int n4) {
    int stride = gridDim.x * blockDim.x;
    for (int i4 = blockIdx.x * blockDim.x + threadIdx.x; i4 < n4; i4 += stride) {
        f4 v = __builtin_nontemporal_load(&in[i4]);
        int c4  = i4 & 3;          // float4 within 16-float sub-chunk
        int sub = (i4 >> 2) & 3;   // 2*j + i
        int pix = i4 >> 4;         // (b, h, w)
        int w = pix & 255;
        int h = (pix >> 8) & 255;
        int b = pix >> 16;
        int i = sub & 1;
        int j = sub >> 1;
        int x = (h << 1) | i;      // output row
        int y = (w << 1) | j;      // output col
        int opix = ((((b << 9) | x) << 9) | y);
        int o4   = (opix << 2) | c4;
        __builtin_nontemporal_store(v, &out[o4]);
    }
}

extern "C" void kernel_launch(void* const* d_in, const int* in_sizes, int n_in,
                              void* d_out, int out_size, void* d_ws, size_t ws_size,
                              hipStream_t stream) {
    const f4* in = (const f4*)d_in[0];
    f4* out = (f4*)d_out;
    int n4 = out_size / 4;  // 16,777,216 float4s
    dim3 block(256);
    dim3 grid(2048);        // 8 blocks/CU, grid-stride covers the rest
    hipLaunchKernelGGL(Conv2DSubPixel_44032004718623_kernel, grid, block, 0,
                       stream, in, out, n4);
}